// Round 3
// baseline (939.543 us; speedup 1.0000x reference)
//
#include <hip/hip_runtime.h>
#include <math.h>

typedef __bf16 bf16x8_t __attribute__((ext_vector_type(8)));
typedef unsigned short u16x8_t __attribute__((ext_vector_type(8)));
typedef float f32x4_t __attribute__((ext_vector_type(4)));
// dword-aligned-only vector loads (global_load_dwordxN needs just 4B align)
typedef float f32x4u __attribute__((ext_vector_type(4), aligned(4)));
typedef float f32x2u __attribute__((ext_vector_type(2), aligned(4)));

#define NB_TOTAL 200000
#define W1P_ELEMS 51200   // 10 ktiles * 10 jtiles * 64 lanes * 8
#define W2P_ELEMS 10240   // 5 ktiles * 4 jtiles * 64 lanes * 8

__device__ __forceinline__ unsigned short f2bf(float f) {
    unsigned int u = __builtin_bit_cast(unsigned int, f);
    u += 0x7fffu + ((u >> 16) & 1u);   // RNE
    return (unsigned short)(u >> 16);
}

__device__ __forceinline__ bf16x8_t pack8(const float* x) {
    u16x8_t u;
    #pragma unroll
    for (int i = 0; i < 8; ++i) u[i] = f2bf(x[i]);
    return __builtin_bit_cast(bf16x8_t, u);
}

__global__ void kzero(float* __restrict__ out, int n) {
    int i = blockIdx.x * 256 + threadIdx.x;
    if (i < n) out[i] = 0.0f;
}

// Repack W1 (320x160) and W2 (160x64) into MFMA B-fragment order, fp32 -> bf16.
// B-frag for mfma_f32_16x16x32_bf16: lane L holds B[k = (L>>4)*8 + e][n = L&15].
__global__ void krepack(const float* __restrict__ W1, const float* __restrict__ W2,
                        const int* __restrict__ batch, int nb,
                        unsigned short* __restrict__ w1p, unsigned short* __restrict__ w2p,
                        int* __restrict__ flagp) {
    int tid = blockIdx.x * 256 + threadIdx.x;
    if (tid == 0) *flagp = (batch[nb - 1] == 0) ? 1 : 0;   // int64 batch detection
    if (tid < W1P_ELEMS) {
        int e = tid & 7, L = (tid >> 3) & 63, q = tid >> 9;
        int kt = q % 10, j = q / 10;
        int krow = kt * 32 + (L >> 4) * 8 + e;
        int col  = j * 16 + (L & 15);
        w1p[tid] = f2bf(W1[krow * 160 + col]);
    } else if (tid < W1P_ELEMS + W2P_ELEMS) {
        int s = tid - W1P_ELEMS;
        int e = s & 7, L = (s >> 3) & 63, q = s >> 9;
        int kt = q % 5, j = q / 5;
        int krow = kt * 32 + (L >> 4) * 8 + e;
        int col  = j * 16 + (L & 15);
        w2p[s] = f2bf(W2[krow * 64 + col]);
    }
}

// Fused kernel, register-direct A-fragments (no feature staging in LDS).
// 1 block = 64 nodes, 4 waves; wave w owns node rows [16w, 16w+16).
// A-frag lane mapping (m = L&15, k = quad*8+e) => each lane needs 8 CONSECUTIVE
// feature cols of ONE node => buildable straight from global:
//   kt0-3: h[gm, kt*32+quad*8 ..+8)            (32 B contiguous per lane)
//   kt4-5: ||v|| of 8 consecutive channels     (96 B contiguous per lane)
//   kt6-9: (tr,frob) of 4 consecutive channels (144 B contiguous per lane)
// LDS only for Hs [64][168] bf16 (21504 B) with alph f32 [64][68] overlay.
// => 6 blocks/CU (24 waves, 75% occ), ONE __syncthreads (guards Hs->alph overlay).
__launch_bounds__(256, 6)
__global__ void kmega(const float* __restrict__ hA, const float* __restrict__ vA,
                      const float* __restrict__ tA, const float* __restrict__ lfA,
                      const int* __restrict__ batch,
                      const float* __restrict__ b1, const float* __restrict__ b2,
                      const unsigned short* __restrict__ w1p,
                      const unsigned short* __restrict__ w2p,
                      const int* __restrict__ flagp,
                      float* __restrict__ out)
{
    __shared__ __align__(16) unsigned char smem[21504];
    unsigned short* Hs = (unsigned short*)smem;   // [64][168] bf16
    float* alph = (float*)smem;                   // [64][68] f32 overlay

    const int tid  = threadIdx.x;
    const int w    = tid >> 6;
    const int L    = tid & 63;
    const int quad = L >> 4;
    const int c16  = L & 15;
    const long gbase = (long)blockIdx.x * 64;
    const long gm    = gbase + w * 16 + c16;   // node backing this lane's A-frag row

    // ---------------- phase 1: A-fragments direct from global ----------------
    bf16x8_t afrag[10];
    {   // h: kt 0..3
        const float* hp = hA + gm * 128 + quad * 8;
        #pragma unroll
        for (int kt = 0; kt < 4; ++kt) {
            float x[8];
            *(f32x4u*)(x)     = *(const f32x4u*)(hp + kt * 32);
            *(f32x4u*)(x + 4) = *(const f32x4u*)(hp + kt * 32 + 4);
            afrag[kt] = pack8(x);
        }
    }
    {   // v_norm: kt 4..5 (channels c0 = kt2*32 + quad*8, 8 channels x 3 floats)
        const float* vp = vA + gm * 192 + quad * 24;
        #pragma unroll
        for (int kt2 = 0; kt2 < 2; ++kt2) {
            float x[24];
            #pragma unroll
            for (int q = 0; q < 6; ++q)
                *(f32x4u*)(x + 4 * q) = *(const f32x4u*)(vp + kt2 * 96 + 4 * q);
            float nm[8];
            #pragma unroll
            for (int c = 0; c < 8; ++c)
                nm[c] = sqrtf(x[3*c]*x[3*c] + x[3*c+1]*x[3*c+1] + x[3*c+2]*x[3*c+2]);
            afrag[4 + kt2] = pack8(nm);
        }
    }
    {   // t invariants: kt 6..9 (channels c0 = kt4*16 + quad*4, 4 channels x 9 floats)
        const float* tp = tA + gm * 576 + quad * 36;
        #pragma unroll
        for (int kt4 = 0; kt4 < 4; ++kt4) {
            float x[36];
            #pragma unroll
            for (int q = 0; q < 9; ++q)
                *(f32x4u*)(x + 4 * q) = *(const f32x4u*)(tp + kt4 * 144 + 4 * q);
            float ti[8];
            #pragma unroll
            for (int c = 0; c < 4; ++c) {
                const float* b = x + 9 * c;
                ti[2*c]   = b[0] + b[4] + b[8];
                ti[2*c+1] = sqrtf(b[0]*b[0] + b[1]*b[1] + b[2]*b[2] + b[3]*b[3] + b[4]*b[4] +
                                  b[5]*b[5] + b[6]*b[6] + b[7]*b[7] + b[8]*b[8]);
            }
            afrag[6 + kt4] = pack8(ti);
        }
    }

    // ---------------- phase 2: Hs = silu(F @ W1 + b1) ----------------
    {
        const u16x8_t* W1f = (const u16x8_t*)w1p;
        for (int j = 0; j < 10; ++j) {
            f32x4_t acc = {0.f, 0.f, 0.f, 0.f};
            #pragma unroll
            for (int kt = 0; kt < 10; ++kt) {
                bf16x8_t bfrag = __builtin_bit_cast(bf16x8_t, W1f[(j * 10 + kt) * 64 + L]);
                acc = __builtin_amdgcn_mfma_f32_16x16x32_bf16(afrag[kt], bfrag, acc, 0, 0, 0);
            }
            const float bias = b1[j * 16 + c16];
            #pragma unroll
            for (int r = 0; r < 4; ++r) {   // D: row m = quad*4 + r, col n = c16
                float xx = acc[r] + bias;
                float sv = xx / (1.0f + __expf(-xx));   // SiLU
                Hs[(w * 16 + quad * 4 + r) * 168 + j * 16 + c16] = f2bf(sv);
            }
        }
    }

    // A-frags for GEMM2 (own-wave Hs rows, program-ordered -> no barrier needed)
    bf16x8_t a2[5];
    {
        const unsigned short* hrow = Hs + (w * 16 + c16) * 168;
        #pragma unroll
        for (int kt = 0; kt < 5; ++kt)
            a2[kt] = __builtin_bit_cast(bf16x8_t, *(const u16x8_t*)(hrow + kt * 32 + quad * 8));
    }
    __syncthreads();   // all waves done reading Hs -> alph overlay safe

    // ---------------- phase 3: alph = H @ W2 + b2 (fp32, LDS) ----------------
    {
        const u16x8_t* W2f = (const u16x8_t*)w2p;
        #pragma unroll
        for (int j = 0; j < 4; ++j) {
            f32x4_t acc = {0.f, 0.f, 0.f, 0.f};
            #pragma unroll
            for (int kt = 0; kt < 5; ++kt) {
                bf16x8_t bfrag = __builtin_bit_cast(bf16x8_t, W2f[(j * 5 + kt) * 64 + L]);
                acc = __builtin_amdgcn_mfma_f32_16x16x32_bf16(a2[kt], bfrag, acc, 0, 0, 0);
            }
            const float bias = b2[j * 16 + c16];
            #pragma unroll
            for (int r = 0; r < 4; ++r)
                alph[(w * 16 + quad * 4 + r) * 68 + j * 16 + c16] = acc[r] + bias;
        }
    }

    // ---------------- phase 4: gate, symmetrize, rotate, pool ----------------
    const int is64 = *flagp;
    #pragma unroll 4
    for (int i = 0; i < 16; ++i) {
        const int  n = w * 16 + i;
        const long g = gbase + n;
        const float* tp = tA + g * 576 + 9 * L;   // L2/L3-hot re-read
        const f32x4u t04 = *(const f32x4u*)tp;        // e0..e3
        const f32x4u t48 = *(const f32x4u*)(tp + 4);  // e4..e7
        const float  e8  = tp[8];
        const float alpha = alph[n * 68 + L];         // own-wave rows: no barrier
        // symmetrized gated partials (6 unique entries of 0.5*(M+M^T))
        float p0 = alpha * t04.x;                     // S00
        float p1 = alpha * t48.x;                     // S11
        float p2 = alpha * e8;                        // S22
        float p3 = alpha * 0.5f * (t04.y + t04.w);    // S01
        float p4 = alpha * 0.5f * (t04.z + t48.z);    // S02
        float p5 = alpha * 0.5f * (t48.y + t48.w);    // S12
        #pragma unroll
        for (int off = 32; off >= 1; off >>= 1) {
            p0 += __shfl_xor(p0, off, 64);
            p1 += __shfl_xor(p1, off, 64);
            p2 += __shfl_xor(p2, off, 64);
            p3 += __shfl_xor(p3, off, 64);
            p4 += __shfl_xor(p4, off, 64);
            p5 += __shfl_xor(p5, off, 64);
        }
        if (L < 9) {     // lane j writes output element (j/3, j%3)
            const float* Rp = lfA + g * 9;
            const int r = L / 3, c = L % 3;
            float Ra0 = Rp[3*r], Ra1 = Rp[3*r+1], Ra2 = Rp[3*r+2];
            float Rb0 = Rp[3*c], Rb1 = Rp[3*c+1], Rb2 = Rp[3*c+2];
            // u = S @ Rb (S symmetric), val = Ra . u
            float u0 = p0*Rb0 + p3*Rb1 + p4*Rb2;
            float u1 = p3*Rb0 + p1*Rb1 + p5*Rb2;
            float u2 = p4*Rb0 + p5*Rb1 + p2*Rb2;
            float val = Ra0*u0 + Ra1*u1 + Ra2*u2;
            const int gi = (int)g;
            const int bg = is64 ? batch[2 * gi] : batch[gi];
            atomicAdd(out + (long)bg * 9 + L, val);
        }
    }
}

extern "C" void kernel_launch(void* const* d_in, const int* in_sizes, int n_in,
                              void* d_out, int out_size, void* d_ws, size_t ws_size,
                              hipStream_t stream)
{
    (void)n_in; (void)ws_size;
    const float* hA  = (const float*)d_in[0];
    const float* vA  = (const float*)d_in[1];
    const float* tA  = (const float*)d_in[2];
    const float* lfA = (const float*)d_in[3];
    const int*   bt  = (const int*)d_in[4];
    const float* W1  = (const float*)d_in[5];
    const float* b1  = (const float*)d_in[6];
    const float* W2  = (const float*)d_in[7];
    const float* b2  = (const float*)d_in[8];
    float* out = (float*)d_out;

    unsigned short* w1p = (unsigned short*)d_ws;                        // 102400 B
    unsigned short* w2p = (unsigned short*)((char*)d_ws + 102400);      // 20480 B
    int* flagp = (int*)((char*)d_ws + 122880);                          // 4 B

    kzero<<<(out_size + 255) / 256, 256, 0, stream>>>(out, out_size);
    krepack<<<240, 256, 0, stream>>>(W1, W2, bt, in_sizes[4], w1p, w2p, flagp);
    kmega<<<NB_TOTAL / 64, 256, 0, stream>>>(hA, vA, tA, lfA, bt, b1, b2, w1p, w2p, flagp, out);
}